// Round 4
// baseline (169.959 us; speedup 1.0000x reference)
//
#include <hip/hip_runtime.h>

typedef _Float16 f16;
typedef _Float16 f16x4 __attribute__((ext_vector_type(4)));
typedef _Float16 f16x8 __attribute__((ext_vector_type(8)));
typedef float    f32x4 __attribute__((ext_vector_type(4)));

#define NB   8
#define TE   2048
#define TD   2048
#define DIM  256
#define NSPLIT 3
#define LOG2E 1.44269504088896340736f

#define AS1(p) ((const __attribute__((address_space(1))) void*)(p))
#define AS3(p) ((__attribute__((address_space(3))) void*)(p))
#define MFMA16(a,b,c) __builtin_amdgcn_mfma_f32_16x16x32_f16((a),(b),(c),0,0,0)

__device__ __forceinline__ unsigned lds_u32(void* p) {
    return (unsigned)(size_t)((__attribute__((address_space(3))) void*)p);
}
// ds_read_b64_tr_b16: lane reads its OWN 8B payload at its address; fixed in-group
// permutation delivers out[l][j] = block[row j][col l&15] when per-lane addr =
// block_base + (l&15)*8 for the 4x16 row-major (128 B) block. (m156 semantics.)
__device__ __forceinline__ f16x4 tr_rd0(unsigned a) {
    f16x4 r;
    asm volatile("ds_read_b64_tr_b16 %0, %1" : "=v"(r) : "v"(a));
    return r;
}
__device__ __forceinline__ f16x4 tr_rd1(unsigned a) {   // +2048 B = next e4 subtile row
    f16x4 r;
    asm volatile("ds_read_b64_tr_b16 %0, %1 offset:2048" : "=v"(r) : "v"(a));
    return r;
}

// ---------------- prep: enc fp32 -> f16, same layout ----------------
__global__ __launch_bounds__(256) void prep_kernel(const float* __restrict__ enc,
                                                   f16* __restrict__ ench) {
    size_t i = ((size_t)blockIdx.x * 256 + threadIdx.x) * 8;
    float4 v0 = *(const float4*)(enc + i);
    float4 v1 = *(const float4*)(enc + i + 4);
    f16x8 o;
    o[0]=(f16)v0.x; o[1]=(f16)v0.y; o[2]=(f16)v0.z; o[3]=(f16)v0.w;
    o[4]=(f16)v1.x; o[5]=(f16)v1.y; o[6]=(f16)v1.z; o[7]=(f16)v1.w;
    *(f16x8*)(ench + i) = o;
}

// ---------------- fused attention, symmetric 4-wave, single staged enc tile ----------------
// Identical to the round-2 (passing) kernel EXCEPT the PV A-fragment fetch:
// 16 batched ds_read_b64_tr_b16 (correct per-lane payload addressing: base + tcol*8)
// replace the 64 ds_read_u16 gathers. One lgkmcnt(0)+sched_barrier(0) fence (rule #18)
// between the tr batch and the MFMA cluster.
// Subtiled layout: half(e,d) = ((e>>2)*16 + (d>>4))*64 + (e&3)*16 + (d&15)
//   QK reads rows via ds_read_b128; PV reads columns via tr-reads (1 subtile = 1 block).
// LDS 38,400 B -> 3 blocks/CU (12 waves/CU).
#define LDS_P  32768
#define LDS_X  37888

__global__ __launch_bounds__(256, 3) void attn_kernel(
        const float* __restrict__ dec32,
        const f16*  __restrict__ enc_h,
        f16*   __restrict__ ctxp,
        float* __restrict__ m_arr,
        float* __restrict__ l_arr,
        int nsplit) {
    __shared__ __align__(16) char lds[38400];
    const int tid  = threadIdx.x;
    const int lane = tid & 63;
    const int wv   = tid >> 6;
    const int th   = wv >> 1;
    const int eh   = wv & 1;
    const int tcol = lane & 15;
    const int q    = lane >> 4;

    int fid = blockIdx.x + 32 * (blockIdx.y + 8 * blockIdx.z);
    const int b  = fid & 7;
    const int xb = (fid >> 3) & 31;
    const int z  = fid >> 8;
    const int t0 = xb * 64;
    const int tile0 = (64 * z) / nsplit;
    const int tile1 = (64 * (z + 1)) / nsplit;
    const int iters = tile1 - tile0;

    const char* encb = (const char*)(enc_h + (size_t)b * TE * DIM);

    // staging: chunk c = i*256 + wv*64 + lane (16B); inverse subtile map
    const int c0  = wv * 64 + lane;
    const int e_l = ((c0 >> 7) << 2) | ((c0 >> 1) & 3);
    const int d_l = (((c0 >> 3) & 15) << 4) | ((c0 & 1) << 3);
    const int stage_goff = e_l * (DIM * 2) + d_l * 2;
    char* stage_dst = lds + wv * 1024;

    // QK row read: e = eh*16+tcol, d-octet = ks*32+q*8
    const int qk_base = (eh * 4 + (tcol >> 2)) * 2048 + (q >> 1) * 128 + (tcol & 3) * 32 + (q & 1) * 16;
    // PV tr-read: subtile (e4=q*2, d16=eh*8+dm) base + tcol*8  (j4..7 via offset:2048)
    const unsigned pv_base = (unsigned)(q * 4096 + eh * 1024 + tcol * 8);
    const unsigned lds_base = lds_u32(lds);
    char* pb = lds + LDS_P + th * 2560;           // P: 32 rows x 80 B
    float* exch = (float*)(lds + LDS_X);          // 4 waves x 32 floats

    // Q fragments: B[k=d][n=t]
    f16x8 qf[2][8];
    {
        const float* qp = dec32 + ((size_t)b * TD + t0 + th * 32) * DIM;
        #pragma unroll
        for (int tn = 0; tn < 2; tn++)
            #pragma unroll
            for (int ks = 0; ks < 8; ks++) {
                const float* p = qp + (size_t)(tn * 16 + tcol) * DIM + ks * 32 + q * 8;
                float4 u = *(const float4*)(p);
                float4 v = *(const float4*)(p + 4);
                f16x8 o;
                o[0]=(f16)u.x; o[1]=(f16)u.y; o[2]=(f16)u.z; o[3]=(f16)u.w;
                o[4]=(f16)v.x; o[5]=(f16)v.y; o[6]=(f16)v.z; o[7]=(f16)v.w;
                qf[tn][ks] = o;
            }
    }

    { // stage tile0 -> buf0
        const char* s = encb + (size_t)tile0 * 16384 + stage_goff;
        #pragma unroll
        for (int i = 0; i < 4; i++)
            __builtin_amdgcn_global_load_lds(AS1(s + i * 4096), AS3(stage_dst + i * 4096), 16, 0, 0);
    }

    const f32x4 zero4 = {0.f, 0.f, 0.f, 0.f};
    float m_[2] = {-INFINITY, -INFINITY};
    float l_[2] = {0.f, 0.f};
    f32x4 ctx[8][2];
    #pragma unroll
    for (int dm = 0; dm < 8; dm++) { ctx[dm][0] = zero4; ctx[dm][1] = zero4; }

    __syncthreads();   // NAT(0) staged & drained

    for (int it = 0; it < iters; ++it) {
        const int nat = (it & 1) << 14;
        // ---- W1: QK quadrant (e16 x t32) ----
        f32x4 st[2] = {zero4, zero4};
        const char* natp = lds + nat + qk_base;
        #pragma unroll
        for (int ks = 0; ks < 8; ks++) {
            f16x8 af = *(const f16x8*)(natp + ks * 256);
            st[0] = MFMA16(af, qf[0][ks], st[0]);
            st[1] = MFMA16(af, qf[1][ks], st[1]);
        }
        float mx[2];
        #pragma unroll
        for (int tn = 0; tn < 2; tn++) {
            float m0 = fmaxf(fmaxf(st[tn][0], st[tn][1]), fmaxf(st[tn][2], st[tn][3]));
            m0 = fmaxf(m0, __shfl_xor(m0, 16, 64));
            m0 = fmaxf(m0, __shfl_xor(m0, 32, 64));
            mx[tn] = m0;
        }
        if (q == 0) { exch[wv * 32 + tcol] = mx[0]; exch[wv * 32 + 16 + tcol] = mx[1]; }
        __syncthreads();   // bar1
        // ---- W2 ----
        if (it + 1 < iters) {   // stage next tile early; drained at bar2
            const char* s = encb + (size_t)(tile0 + it + 1) * 16384 + stage_goff;
            char* dd = stage_dst + (((it + 1) & 1) << 14);
            #pragma unroll
            for (int i = 0; i < 4; i++)
                __builtin_amdgcn_global_load_lds(AS1(s + i * 4096), AS3(dd + i * 4096), 16, 0, 0);
        }
        bool anyb = false;
        float al[2], s4v[2];
        #pragma unroll
        for (int tn = 0; tn < 2; tn++) {
            float ox = exch[(wv ^ 1) * 32 + tn * 16 + tcol];
            float mn = fmaxf(m_[tn], fmaxf(mx[tn], ox));
            al[tn] = __builtin_amdgcn_exp2f((m_[tn] - mn) * LOG2E);
            anyb = anyb || (mn > m_[tn]);
            m_[tn] = mn;
            f16x4 pv;
            #pragma unroll
            for (int r = 0; r < 4; r++)
                pv[r] = (f16)__builtin_amdgcn_exp2f((st[tn][r] - mn) * LOG2E);
            *(f16x4*)(pb + (tn * 16 + tcol) * 80 + eh * 32 + q * 8) = pv;
            float s4 = ((float)pv[0] + (float)pv[1]) + ((float)pv[2] + (float)pv[3]);
            s4 += __shfl_xor(s4, 16, 64);
            s4 += __shfl_xor(s4, 32, 64);
            s4v[tn] = s4;
        }
        if (__any(anyb)) {
            #pragma unroll
            for (int tn = 0; tn < 2; tn++) {
                l_[tn] *= al[tn];
                #pragma unroll
                for (int dm = 0; dm < 8; dm++) {
                    ctx[dm][tn][0] *= al[tn]; ctx[dm][tn][1] *= al[tn];
                    ctx[dm][tn][2] *= al[tn]; ctx[dm][tn][3] *= al[tn];
                }
            }
        }
        l_[0] += s4v[0]; l_[1] += s4v[1];
        __syncthreads();   // bar2: P visible, stage(it+1) drained
        // ---- C: PV (d-half 128 x t32); A-fragments via batched tr-reads ----
        f16x8 pf0 = *(const f16x8*)(pb + tcol * 80 + q * 16);
        f16x8 pf1 = *(const f16x8*)(pb + (16 + tcol) * 80 + q * 16);
        const unsigned trb = lds_base + (unsigned)nat + pv_base;
        f16x4 tr[16];
        #pragma unroll
        for (int dm = 0; dm < 8; dm++) {
            tr[2 * dm]     = tr_rd0(trb + (unsigned)(dm * 128));   // e = q*8 + 0..3
            tr[2 * dm + 1] = tr_rd1(trb + (unsigned)(dm * 128));   // e = q*8 + 4..7
        }
        asm volatile("s_waitcnt lgkmcnt(0)" ::: "memory");
        __builtin_amdgcn_sched_barrier(0);
        #pragma unroll
        for (int dm = 0; dm < 8; dm++) {
            f16x8 af = __builtin_shufflevector(tr[2 * dm], tr[2 * dm + 1], 0, 1, 2, 3, 4, 5, 6, 7);
            ctx[dm][0] = MFMA16(af, pf0, ctx[dm][0]);
            ctx[dm][1] = MFMA16(af, pf1, ctx[dm][1]);
        }
        // no barrier: C merges into next W1 (different NAT buffer, P protected by bar1)
    }

    // ---- epilogue: merge l across eh-partners, write normalized f16 partials ----
    if (q == 0) { exch[wv * 32 + tcol] = l_[0]; exch[wv * 32 + 16 + tcol] = l_[1]; }
    __syncthreads();
    float lt[2];
    lt[0] = l_[0] + exch[(wv ^ 1) * 32 + tcol];
    lt[1] = l_[1] + exch[(wv ^ 1) * 32 + 16 + tcol];
    size_t row0 = (size_t)(z * NB + b) * TD + t0 + th * 32;
    #pragma unroll
    for (int tn = 0; tn < 2; tn++) {
        float inv = 1.0f / lt[tn];
        size_t rb = (row0 + tn * 16 + tcol) * DIM + eh * 128;
        #pragma unroll
        for (int dm = 0; dm < 8; dm++) {
            f16x4 cv;
            #pragma unroll
            for (int r = 0; r < 4; r++) cv[r] = (f16)(ctx[dm][tn][r] * inv);
            *(f16x4*)(ctxp + rb + dm * 16 + q * 4) = cv;
        }
    }
    if (eh == 0 && q == 0) {
        int mi = (z * NB + b) * TD + t0 + th * 32 + tcol;
        m_arr[mi]      = m_[0];
        m_arr[mi + 16] = m_[1];
        l_arr[mi]      = lt[0];
        l_arr[mi + 16] = lt[1];
    }
}

// ---------------- combine: merge nsplit normalized partials + decoder passthrough ----------
__global__ __launch_bounds__(256) void combine_kernel(const float* __restrict__ dec32,
        const f16* __restrict__ ctxp, const float* __restrict__ m_arr,
        const float* __restrict__ l_arr, float* __restrict__ out, int nsplit) {
    int idx  = blockIdx.x * 256 + threadIdx.x;
    int trow = idx >> 5;              // b*TD + t
    int dg   = (idx & 31) * 8;
    float m0[NSPLIT], l0[NSPLIT], M = -INFINITY;
    #pragma unroll
    for (int s = 0; s < NSPLIT; s++) if (s < nsplit) {
        m0[s] = m_arr[s * (NB * TD) + trow];
        l0[s] = l_arr[s * (NB * TD) + trow];
        M = fmaxf(M, m0[s]);
    }
    float L = 0.f, w[NSPLIT];
    #pragma unroll
    for (int s = 0; s < NSPLIT; s++) if (s < nsplit) {
        w[s] = __builtin_amdgcn_exp2f((m0[s] - M) * LOG2E) * l0[s];
        L += w[s];
    }
    float invL = 1.0f / L;
    float acc[8] = {0.f,0.f,0.f,0.f,0.f,0.f,0.f,0.f};
    #pragma unroll
    for (int s = 0; s < NSPLIT; s++) if (s < nsplit) {
        f16x8 v = *(const f16x8*)(ctxp + ((size_t)s * (NB * TD) + trow) * DIM + dg);
        float ws = w[s] * invL;
        #pragma unroll
        for (int j = 0; j < 8; j++) acc[j] += ws * (float)v[j];
    }
    float4 d0 = *(const float4*)(dec32 + (size_t)trow * DIM + dg);
    float4 d1 = *(const float4*)(dec32 + (size_t)trow * DIM + dg + 4);
    float* ob = out + (size_t)trow * 512;
    *(float4*)(ob + dg)     = d0;
    *(float4*)(ob + dg + 4) = d1;
    float4 c0, c1;
    c0.x=acc[0]; c0.y=acc[1]; c0.z=acc[2]; c0.w=acc[3];
    c1.x=acc[4]; c1.y=acc[5]; c1.z=acc[6]; c1.w=acc[7];
    *(float4*)(ob + 256 + dg)     = c0;
    *(float4*)(ob + 256 + dg + 4) = c1;
}

extern "C" void kernel_launch(void* const* d_in, const int* in_sizes, int n_in,
                              void* d_out, int out_size, void* d_ws, size_t ws_size,
                              hipStream_t stream) {
    (void)in_sizes; (void)n_in;
    const float* enc = (const float*)d_in[0];
    const float* dec = (const float*)d_in[1];
    float* out = (float*)d_out;

    const size_t MLB = (size_t)NSPLIT * NB * TD * 4;      // 196,608 per array
    const size_t HB  = (size_t)NB * TE * DIM * 2;         // 8,388,608
    const size_t CSL = (size_t)NB * TD * DIM * 2;         // 8,388,608 per split

    float* m_arr = (float*)d_ws;
    float* l_arr = (float*)((char*)d_ws + MLB);
    f16*   ench  = (f16*)((char*)d_ws + 2 * MLB);
    f16*   ctxp  = (f16*)((char*)d_ws + 2 * MLB + HB);

    int nsplit;
    if      (ws_size >= 2 * MLB + HB + 3 * CSL) nsplit = 3;
    else if (ws_size >= 2 * MLB + HB + 2 * CSL) nsplit = 2;
    else { hipMemsetAsync(d_out, 0, (size_t)out_size * sizeof(float), stream); return; }

    prep_kernel<<<2048, 256, 0, stream>>>(enc, ench);
    attn_kernel<<<dim3(32, 8, nsplit), 256, 0, stream>>>(dec, ench, ctxp, m_arr, l_arr, nsplit);
    combine_kernel<<<2048, 256, 0, stream>>>(dec, ctxp, m_arr, l_arr, out, nsplit);
}

// Round 5
// 145.627 us; speedup vs baseline: 1.1671x; 1.1671x over previous
//
#include <hip/hip_runtime.h>

typedef _Float16 f16;
typedef _Float16 f16x2 __attribute__((ext_vector_type(2)));
typedef _Float16 f16x4 __attribute__((ext_vector_type(4)));
typedef _Float16 f16x8 __attribute__((ext_vector_type(8)));
typedef float    f32x16 __attribute__((ext_vector_type(16)));

#define NB   8
#define TE   2048
#define TD   2048
#define DIM  256
#define NBTD (NB * TD)
#define LOG2E 1.44269504088896340736f

#define AS1(p) ((const __attribute__((address_space(1))) void*)(p))
#define AS3(p) ((__attribute__((address_space(3))) void*)(p))
#define MFMA32(a,b,c) __builtin_amdgcn_mfma_f32_32x32x16_f16((a),(b),(c),0,0,0)
#define SHUF8(x,y) __builtin_shufflevector((x),(y),0,1,2,3,4,5,6,7)

__device__ __forceinline__ unsigned lds_u32(void* p) {
    return (unsigned)(size_t)((__attribute__((address_space(3))) void*)p);
}
// ds_read_b64_tr_b16 (validated round 4): per-lane 8B payload at its own addr;
// in-group permutation delivers out[l][j] = block[row j][col l&15] for the 4x16
// row-major 128B block when per-lane addr = block_base + (l&15)*8.
__device__ __forceinline__ f16x4 tr_rd0(unsigned a) {
    f16x4 r;
    asm volatile("ds_read_b64_tr_b16 %0, %1" : "=v"(r) : "v"(a));
    return r;
}
__device__ __forceinline__ f16x4 tr_rd1(unsigned a) {   // +2048 = next e4 subtile row
    f16x4 r;
    asm volatile("ds_read_b64_tr_b16 %0, %1 offset:2048" : "=v"(r) : "v"(a));
    return r;
}

// ---------------- prep: enc fp32 -> f16, same layout ----------------
__global__ __launch_bounds__(256) void prep_kernel(const float* __restrict__ enc,
                                                   f16* __restrict__ ench) {
    size_t i = ((size_t)blockIdx.x * 256 + threadIdx.x) * 8;
    float4 v0 = *(const float4*)(enc + i);
    float4 v1 = *(const float4*)(enc + i + 4);
    f16x8 o;
    o[0]=(f16)v0.x; o[1]=(f16)v0.y; o[2]=(f16)v0.z; o[3]=(f16)v0.w;
    o[4]=(f16)v1.x; o[5]=(f16)v1.y; o[6]=(f16)v1.z; o[7]=(f16)v1.w;
    *(f16x8*)(ench + i) = o;
}

// ---------------- fused attention: wave-decoupled, 32x32 MFMA, 1 barrier/iter -----------
// Block = 4 waves, each owns 32 t-columns (t = t0 + wv*32 + (lane&31)) for the FULL
// pipeline: QK (32x32x16, e32 x t32, 16 k-steps) -> lane-local softmax (rowmax = local
// 16-max + one shfl_xor(32)) -> P to per-wave LDS scratch (same-wave in-order DS, no
// barrier) -> PV (8 dm x 2 ks, A = enc^T via tr-reads). No cross-wave exchange at all.
// One __syncthreads per iter (NAT dbuf); staging(it+1) issued at iter top -> vmcnt(0)
// drain at iter-end barrier is a full window later (~free).
// NAT subtiled layout (proven r2/r4): half(e,d) = ((e>>2)*16 + (d>>4))*64 + (e&3)*16 + (d&15)
// nsplit=4 (16 e-tiles/split); split 3 partials -> out (f32); m/l packed f16x2
// (m snapped to f16 before use -> storage exact). LDS 43,008 B, 2 blocks/CU.
__global__ __launch_bounds__(256, 2) void attn_kernel(
        const float* __restrict__ dec32,
        const f16*  __restrict__ enc_h,
        f16*   __restrict__ ctxp,
        f16x2* __restrict__ ml,
        float* __restrict__ out) {
    __shared__ __align__(16) char lds[43008];
    const int tid  = threadIdx.x;
    const int lane = tid & 63;
    const int wv   = tid >> 6;
    const int t5   = lane & 31;   // this lane's t-column (within wave tile)
    const int hi   = lane >> 5;

    // fid%8 = XCD (heuristic): pin batch b to XCD b -> enc[b] (1MB) + dec[b] (2.1MB) L2-resident
    const int fid = blockIdx.x + 16 * (blockIdx.y + 8 * blockIdx.z);
    const int b    = fid & 7;
    const int rest = fid >> 3;
    const int xb   = rest & 15;
    const int z    = rest >> 4;           // 0..3
    const int t0   = xb * 128 + wv * 32;
    const int tile0 = z * 16;             // 16 e-tiles of 32 per split
    const int ITERS = 16;

    const char* encb = (const char*)(enc_h + (size_t)b * TE * DIM);

    // staging map (proven r2/r4): chunk c = i*256 + wv*64 + lane (16B), inverse subtile map
    const int c0  = wv * 64 + lane;
    const int e_l = ((c0 >> 7) << 2) | ((c0 >> 1) & 3);
    const int d_l = (((c0 >> 3) & 15) << 4) | ((c0 & 1) << 3);
    const int stage_goff = e_l * (DIM * 2) + d_l * 2;
    char* stage_dst = lds + wv * 1024;

    // QK A-read (row e = lane&31, d-window ks*16 + hi*8, f16x8):
    const int qk_base = ((lane & 31) >> 2) * 2048 + (lane & 3) * 32 + hi * 16;
    // PV tr-read base: subtile(e4 = ks*4 + hi*2, d16 = dm*2 + ((lane>>4)&1)), payload + (l&15)*8
    const unsigned tr_base = (unsigned)(hi * 4096 + ((lane >> 4) & 1) * 128 + (lane & 15) * 8);
    const unsigned lds_base = lds_u32(lds);
    char* pb = lds + 32768 + wv * 2560;   // per-wave P scratch: [t32][e32] f16, pitch 80

    // Q fragments: B[k = ks*16 + hi*8 + j][n = t5]  (16 ks x f16x8 = 64 VGPR)
    f16x8 qf[16];
    {
        const float* qrow = dec32 + ((size_t)b * TD + t0 + t5) * DIM + hi * 8;
        #pragma unroll
        for (int ks = 0; ks < 16; ks++) {
            float4 u = *(const float4*)(qrow + ks * 16);
            float4 v = *(const float4*)(qrow + ks * 16 + 4);
            f16x8 o;
            o[0]=(f16)u.x; o[1]=(f16)u.y; o[2]=(f16)u.z; o[3]=(f16)u.w;
            o[4]=(f16)v.x; o[5]=(f16)v.y; o[6]=(f16)v.z; o[7]=(f16)v.w;
            qf[ks] = o;
        }
    }

    { // stage tile0 -> buf0
        const char* s = encb + (size_t)tile0 * 16384 + stage_goff;
        #pragma unroll
        for (int i = 0; i < 4; i++)
            __builtin_amdgcn_global_load_lds(AS1(s + i * 4096), AS3(stage_dst + i * 4096), 16, 0, 0);
    }

    float m_ = -INFINITY, l_ = 0.f;
    f32x16 ctx[8];
    #pragma unroll
    for (int dm = 0; dm < 8; dm++)
        #pragma unroll
        for (int r = 0; r < 16; r++) ctx[dm][r] = 0.f;

    __syncthreads();   // tile0 staged & drained

    for (int it = 0; it < ITERS; ++it) {
        const int nat = (it & 1) << 14;
        // stage next tile early: drained at THIS iter's end barrier (full window)
        if (it + 1 < ITERS) {
            const char* s = encb + (size_t)(tile0 + it + 1) * 16384 + stage_goff;
            char* dd = lds + (((it + 1) & 1) << 14) + wv * 1024;
            #pragma unroll
            for (int i = 0; i < 4; i++)
                __builtin_amdgcn_global_load_lds(AS1(s + i * 4096), AS3(dd + i * 4096), 16, 0, 0);
        }
        // ---- QK: St[e32][t32], 16 k-steps of 32x32x16 ----
        f32x16 st;
        #pragma unroll
        for (int r = 0; r < 16; r++) st[r] = 0.f;
        const char* natp = lds + nat + qk_base;
        #pragma unroll
        for (int ks = 0; ks < 16; ks++) {
            f16x8 af = *(const f16x8*)(natp + ks * 128);
            st = MFMA32(af, qf[ks], st);
        }
        // ---- softmax (lane-local t-column; e rows split lane vs lane^32) ----
        float x0 = fmaxf(fmaxf(st[0], st[1]),  fmaxf(st[2], st[3]));
        float x1 = fmaxf(fmaxf(st[4], st[5]),  fmaxf(st[6], st[7]));
        float x2 = fmaxf(fmaxf(st[8], st[9]),  fmaxf(st[10], st[11]));
        float x3 = fmaxf(fmaxf(st[12], st[13]), fmaxf(st[14], st[15]));
        float mx = fmaxf(fmaxf(x0, x1), fmaxf(x2, x3));
        mx = fmaxf(mx, __shfl_xor(mx, 32, 64));
        float ms = (float)(f16)fmaxf(m_, mx);   // snap to f16 (>= m_, >= mx - ulp/2)
        float al = __builtin_amdgcn_exp2f((m_ - ms) * LOG2E);
        bool bump = ms > m_;
        m_ = ms;
        float ssum = 0.f;
        #pragma unroll
        for (int g = 0; g < 4; g++) {           // e-group: e = 8g + 4hi + r
            f16x4 pv;
            #pragma unroll
            for (int r = 0; r < 4; r++) {
                float p = __builtin_amdgcn_exp2f((st[4 * g + r] - ms) * LOG2E);
                pv[r] = (f16)p;
                ssum += (float)pv[r];
            }
            *(f16x4*)(pb + t5 * 80 + g * 16 + hi * 8) = pv;   // P[t][e], pitch 80
        }
        ssum += __shfl_xor(ssum, 32, 64);
        l_ = l_ * al + ssum;
        if (__any(bump)) {
            #pragma unroll
            for (int dm = 0; dm < 8; dm++)
                #pragma unroll
                for (int r = 0; r < 16; r++) ctx[dm][r] *= al;
        }
        // ---- PV: ctx[d = dm*32 + row][t32]; A = enc^T tr-reads, B = P (same-wave LDS) ----
        const unsigned trb = lds_base + (unsigned)nat + tr_base;
        #pragma unroll
        for (int ks = 0; ks < 2; ks++) {
            f16x8 pf = *(const f16x8*)(pb + t5 * 80 + ks * 32 + hi * 16);
            const unsigned ab = trb + (unsigned)(ks * 8192);
            f16x4 a0 = tr_rd0(ab);        f16x4 a1 = tr_rd1(ab);
            f16x4 a2 = tr_rd0(ab + 256);  f16x4 a3 = tr_rd1(ab + 256);
            f16x4 a4 = tr_rd0(ab + 512);  f16x4 a5 = tr_rd1(ab + 512);
            f16x4 a6 = tr_rd0(ab + 768);  f16x4 a7 = tr_rd1(ab + 768);
            asm volatile("s_waitcnt lgkmcnt(0)" ::: "memory");
            __builtin_amdgcn_sched_barrier(0);
            ctx[0] = MFMA32(SHUF8(a0, a1), pf, ctx[0]);
            ctx[1] = MFMA32(SHUF8(a2, a3), pf, ctx[1]);
            ctx[2] = MFMA32(SHUF8(a4, a5), pf, ctx[2]);
            ctx[3] = MFMA32(SHUF8(a6, a7), pf, ctx[3]);
            f16x4 b0 = tr_rd0(ab + 1024); f16x4 b1 = tr_rd1(ab + 1024);
            f16x4 b2 = tr_rd0(ab + 1280); f16x4 b3 = tr_rd1(ab + 1280);
            f16x4 b4 = tr_rd0(ab + 1536); f16x4 b5 = tr_rd1(ab + 1536);
            f16x4 b6 = tr_rd0(ab + 1792); f16x4 b7 = tr_rd1(ab + 1792);
            asm volatile("s_waitcnt lgkmcnt(0)" ::: "memory");
            __builtin_amdgcn_sched_barrier(0);
            ctx[4] = MFMA32(SHUF8(b0, b1), pf, ctx[4]);
            ctx[5] = MFMA32(SHUF8(b2, b3), pf, ctx[5]);
            ctx[6] = MFMA32(SHUF8(b4, b5), pf, ctx[6]);
            ctx[7] = MFMA32(SHUF8(b6, b7), pf, ctx[7]);
        }
        __syncthreads();   // NAT dbuf protection + drains staging(it+1) issued a window ago
    }

    // ---- epilogue: normalized partials; split 3 -> out (f32), else ctxp (f16) ----
    const float inv = 1.0f / l_;
    if (z < 3) {
        f16* cb = ctxp + ((size_t)(z * NB + b) * TD + t0 + t5) * DIM;
        #pragma unroll
        for (int dm = 0; dm < 8; dm++)
            #pragma unroll
            for (int g = 0; g < 4; g++) {
                f16x4 cv;
                #pragma unroll
                for (int r = 0; r < 4; r++) cv[r] = (f16)(ctx[dm][4 * g + r] * inv);
                *(f16x4*)(cb + dm * 32 + g * 8 + hi * 4) = cv;   // d = dm*32 + 8g + 4hi + r
            }
    } else {
        float* ob = out + ((size_t)b * TD + t0 + t5) * 512 + 256;
        #pragma unroll
        for (int dm = 0; dm < 8; dm++)
            #pragma unroll
            for (int g = 0; g < 4; g++) {
                float4 cv;
                cv.x = ctx[dm][4 * g]     * inv;
                cv.y = ctx[dm][4 * g + 1] * inv;
                cv.z = ctx[dm][4 * g + 2] * inv;
                cv.w = ctx[dm][4 * g + 3] * inv;
                *(float4*)(ob + dm * 32 + g * 8 + hi * 4) = cv;
            }
    }
    if (hi == 0) {
        f16x2 v; v[0] = (f16)m_; v[1] = (f16)l_;   // m_ exactly f16 (snapped)
        ml[(size_t)z * NBTD + (size_t)b * TD + t0 + t5] = v;
    }
}

// ---------------- combine: merge 4 normalized partials + decoder passthrough ----------
__global__ __launch_bounds__(256) void combine_kernel(const float* __restrict__ dec32,
        const f16* __restrict__ ctxp, const f16x2* __restrict__ ml,
        float* __restrict__ out) {
    int idx  = blockIdx.x * 256 + threadIdx.x;
    int trow = idx >> 5;              // b*TD + t
    int dg   = (idx & 31) * 8;
    float m0[4], l0[4], M = -INFINITY;
    #pragma unroll
    for (int s = 0; s < 4; s++) {
        f16x2 v = ml[(size_t)s * NBTD + trow];
        m0[s] = (float)v[0];
        l0[s] = (float)v[1];
        M = fmaxf(M, m0[s]);
    }
    float L = 0.f, w[4];
    #pragma unroll
    for (int s = 0; s < 4; s++) {
        w[s] = __builtin_amdgcn_exp2f((m0[s] - M) * LOG2E) * l0[s];
        L += w[s];
    }
    float invL = 1.0f / L;
    float acc[8] = {0.f,0.f,0.f,0.f,0.f,0.f,0.f,0.f};
    #pragma unroll
    for (int s = 0; s < 3; s++) {
        f16x8 v = *(const f16x8*)(ctxp + ((size_t)s * NBTD + trow) * DIM + dg);
        float ws = w[s] * invL;
        #pragma unroll
        for (int j = 0; j < 8; j++) acc[j] += ws * (float)v[j];
    }
    {   // split 3 partial lives in out (f32), written by attn; read before overwrite
        const float* o3 = out + (size_t)trow * 512 + 256 + dg;
        float4 p0 = *(const float4*)(o3);
        float4 p1 = *(const float4*)(o3 + 4);
        float w3 = w[3] * invL;
        acc[0] += w3 * p0.x; acc[1] += w3 * p0.y; acc[2] += w3 * p0.z; acc[3] += w3 * p0.w;
        acc[4] += w3 * p1.x; acc[5] += w3 * p1.y; acc[6] += w3 * p1.z; acc[7] += w3 * p1.w;
    }
    float4 d0 = *(const float4*)(dec32 + (size_t)trow * DIM + dg);
    float4 d1 = *(const float4*)(dec32 + (size_t)trow * DIM + dg + 4);
    float* ob = out + (size_t)trow * 512;
    *(float4*)(ob + dg)     = d0;
    *(float4*)(ob + dg + 4) = d1;
    float4 c0, c1;
    c0.x=acc[0]; c0.y=acc[1]; c0.z=acc[2]; c0.w=acc[3];
    c1.x=acc[4]; c1.y=acc[5]; c1.z=acc[6]; c1.w=acc[7];
    *(float4*)(ob + 256 + dg)     = c0;
    *(float4*)(ob + 256 + dg + 4) = c1;
}

extern "C" void kernel_launch(void* const* d_in, const int* in_sizes, int n_in,
                              void* d_out, int out_size, void* d_ws, size_t ws_size,
                              hipStream_t stream) {
    (void)in_sizes; (void)n_in;
    const float* enc = (const float*)d_in[0];
    const float* dec = (const float*)d_in[1];
    float* out = (float*)d_out;

    const size_t MLB = (size_t)4 * NBTD * 4;          // 262,144 (f16x2 per row-split)
    const size_t HB  = (size_t)NB * TE * DIM * 2;     // 8,388,608
    const size_t CSL = (size_t)NBTD * DIM * 2;        // 8,388,608 per split (3 in ws)
    const size_t NEED = MLB + HB + 3 * CSL;           // 33,816,576 <= known-working ws

    if (ws_size < NEED) {
        hipMemsetAsync(d_out, 0, (size_t)out_size * sizeof(float), stream);
        return;
    }
    f16x2* ml   = (f16x2*)d_ws;
    f16*   ench = (f16*)((char*)d_ws + MLB);
    f16*   ctxp = (f16*)((char*)d_ws + MLB + HB);

    prep_kernel<<<2048, 256, 0, stream>>>(enc, ench);
    attn_kernel<<<dim3(16, 8, 4), 256, 0, stream>>>(dec, ench, ctxp, ml, out);
    combine_kernel<<<2048, 256, 0, stream>>>(dec, ctxp, ml, out);
}